// Round 2
// baseline (1695.267 us; speedup 1.0000x reference)
//
#include <hip/hip_runtime.h>

// Problem constants
#define IN_CAPS  1152
#define IN_DIM   8
#define NUM_CAPS 10
#define DIM_CAPS 16
#define B_TOT    256

#define I_T   12   // i's per block -> 96 i-tiles
#define B_BLK 16   // batches per block; 1 per thread

// One routing sweep: recompute u_hat on the fly, softmax(u_hat·V) over n,
// accumulate s[b,n,d] via atomics. V=0 on the first sweep -> c uniform 0.1,
// exactly softmax(b=0).
__global__ __launch_bounds__(256, 6) void pass_kernel(
    const float* __restrict__ x, const float* __restrict__ W,
    const float* __restrict__ Vbuf, float* __restrict__ sbuf) {
  const int tid = threadIdx.x;
  const int n   = tid & 15;        // capsule slot (10 active of 16)
  const int bl  = tid >> 4;        // 0..15 -> batch within tile
  const int b   = blockIdx.x * B_BLK + bl;
  const int i0  = blockIdx.y * I_T;
  const bool active = (n < NUM_CAPS);
  const int nn = active ? n : 0;   // clamp for safe (wasted) loads

  float V[DIM_CAPS], s[DIM_CAPS];
  const float* vp = Vbuf + (b * NUM_CAPS + nn) * DIM_CAPS;
#pragma unroll
  for (int d = 0; d < DIM_CAPS; ++d) {
    V[d] = vp[d];
    s[d] = 0.f;
  }

  const float4* __restrict__ Wp = (const float4*)W;
  const float4* __restrict__ xp = (const float4*)x;

  for (int i = i0; i < i0 + I_T; ++i) {
    // x[b,i,0:8] (broadcast across the 16 n-lanes)
    float4 xa = xp[(size_t)(b * IN_CAPS + i) * 2];
    float4 xb = xp[(size_t)(b * IN_CAPS + i) * 2 + 1];

    const float4* wrow = Wp + (size_t)(nn * IN_CAPS + i) * 32;  // W[n,i,:,:]

    float u[DIM_CAPS];
    float bd = 0.f;
#pragma unroll
    for (int d = 0; d < DIM_CAPS; ++d) {
      float4 wa = wrow[2 * d];
      float4 wb = wrow[2 * d + 1];
      float a = wa.x * xa.x + wa.y * xa.y + wa.z * xa.z + wa.w * xa.w
              + wb.x * xb.x + wb.y * xb.y + wb.z * xb.z + wb.w * xb.w;
      u[d] = a;
      bd += a * V[d];
    }

    // softmax over n (10-wide; logits tiny so no max-subtraction needed)
    float e = active ? __expf(bd) : 0.f;
    float es = e;
#pragma unroll
    for (int m = 1; m < 16; m <<= 1) {
      es += __shfl_xor(es, m, 16);
    }
    float c = e / es;
#pragma unroll
    for (int d = 0; d < DIM_CAPS; ++d) {
      s[d] += c * u[d];
    }
  }

  if (active) {
    float* sp = sbuf + (b * NUM_CAPS + n) * DIM_CAPS;
#pragma unroll
    for (int d = 0; d < DIM_CAPS; ++d) {
      atomicAdd(&sp[d], s[d]);
    }
  }
}

// v = squash(s); V += v (routing) or out = v (final); re-zero s.
__global__ void vupdate_kernel(float* __restrict__ sbuf, float* __restrict__ Vbuf,
                               float* __restrict__ out, int is_final) {
  const int b   = blockIdx.x;            // 0..255
  const int t   = threadIdx.x;           // 0..159 : n = t/16, d = t%16
  const int idx = b * (NUM_CAPS * DIM_CAPS) + t;
  float s  = sbuf[idx];
  float sq = s * s;
#pragma unroll
  for (int m = 1; m < 16; m <<= 1) sq += __shfl_xor(sq, m, 16);  // sum over d
  float norm = sqrtf(sq);
  float v = s * (sq / (1.f + sq)) / (norm + 1e-8f);
  if (is_final) {
    out[idx] = v;
  } else {
    Vbuf[idx] += v;
    sbuf[idx] = 0.f;
  }
}

extern "C" void kernel_launch(void* const* d_in, const int* in_sizes, int n_in,
                              void* d_out, int out_size, void* d_ws, size_t ws_size,
                              hipStream_t stream) {
  const float* x = (const float*)d_in[0];  // [256,1152,8]
  const float* W = (const float*)d_in[1];  // [1,10,1152,16,8]
  float* out  = (float*)d_out;             // [256,10,16]
  float* sbuf = (float*)d_ws;                          // 40960 floats
  float* Vbuf = (float*)d_ws + B_TOT * NUM_CAPS * DIM_CAPS;  // 40960 floats

  // zero s and V (ws is poisoned 0xAA before every call)
  hipMemsetAsync(d_ws, 0, (size_t)2 * B_TOT * NUM_CAPS * DIM_CAPS * sizeof(float), stream);

  for (int p = 0; p < 4; ++p) {
    pass_kernel<<<dim3(B_TOT / B_BLK, IN_CAPS / I_T), 256, 0, stream>>>(x, W, Vbuf, sbuf);
    vupdate_kernel<<<B_TOT, NUM_CAPS * DIM_CAPS, 0, stream>>>(sbuf, Vbuf, out, p == 3);
  }
}

// Round 3
// 1273.552 us; speedup vs baseline: 1.3311x; 1.3311x over previous
//
#include <hip/hip_runtime.h>

// Problem constants
#define IN_CAPS  1152
#define IN_DIM   8
#define NUM_CAPS 10
#define DIM_CAPS 16
#define B_TOT    256

#define I_T   12   // i's per block -> 96 i-tiles
#define B_BLK 32   // batches per block; 2 per thread

// One routing sweep: recompute u_hat on the fly, softmax(u_hat·V) over n,
// accumulate s[b,n,d] via atomics. V=0 on the first sweep -> c uniform 0.1,
// exactly softmax(b=0).
// NOTE: no min-waves in launch_bounds — live state is ~100 VGPRs (V/s/u for
// 2 batches); forcing 6 waves/SIMD (R1) spilled to scratch and was 2x slower.
__global__ __launch_bounds__(256) void pass_kernel(
    const float* __restrict__ x, const float* __restrict__ W,
    const float* __restrict__ Vbuf, float* __restrict__ sbuf) {
  const int tid = threadIdx.x;
  const int n   = tid & 15;        // capsule slot (10 active of 16)
  const int g   = tid >> 4;        // 0..15 -> batch pair
  const int b0  = blockIdx.x * B_BLK + 2 * g;
  const int i0  = blockIdx.y * I_T;
  const bool active = (n < NUM_CAPS);
  const int nn = active ? n : 0;   // clamp for safe (wasted) loads

  float V0[DIM_CAPS], V1[DIM_CAPS], s0[DIM_CAPS], s1[DIM_CAPS];
  const float* vp0 = Vbuf + (b0 * NUM_CAPS + nn) * DIM_CAPS;
  const float* vp1 = Vbuf + ((b0 + 1) * NUM_CAPS + nn) * DIM_CAPS;
#pragma unroll
  for (int d = 0; d < DIM_CAPS; ++d) {
    V0[d] = vp0[d]; V1[d] = vp1[d];
    s0[d] = 0.f;    s1[d] = 0.f;
  }

  const float4* __restrict__ Wp = (const float4*)W;
  const float4* __restrict__ xp = (const float4*)x;

  for (int i = i0; i < i0 + I_T; ++i) {
    // x[b,i,0:8] for the two batches (broadcast across the 16 n-lanes)
    float4 xa0 = xp[(size_t)(b0 * IN_CAPS + i) * 2];
    float4 xb0 = xp[(size_t)(b0 * IN_CAPS + i) * 2 + 1];
    float4 xa1 = xp[(size_t)((b0 + 1) * IN_CAPS + i) * 2];
    float4 xb1 = xp[(size_t)((b0 + 1) * IN_CAPS + i) * 2 + 1];

    const float4* wrow = Wp + (size_t)(nn * IN_CAPS + i) * 32;  // W[n,i,:,:]

    float u0[DIM_CAPS], u1[DIM_CAPS];
    float bd0 = 0.f, bd1 = 0.f;
#pragma unroll
    for (int d = 0; d < DIM_CAPS; ++d) {
      float4 wa = wrow[2 * d];
      float4 wb = wrow[2 * d + 1];
      float a = wa.x * xa0.x + wa.y * xa0.y + wa.z * xa0.z + wa.w * xa0.w
              + wb.x * xb0.x + wb.y * xb0.y + wb.z * xb0.z + wb.w * xb0.w;
      float c = wa.x * xa1.x + wa.y * xa1.y + wa.z * xa1.z + wa.w * xa1.w
              + wb.x * xb1.x + wb.y * xb1.y + wb.z * xb1.z + wb.w * xb1.w;
      u0[d] = a; u1[d] = c;
      bd0 += a * V0[d];
      bd1 += c * V1[d];
    }

    // softmax over n (10-wide; logits tiny so no max-subtraction needed)
    float e0 = active ? __expf(bd0) : 0.f;
    float e1 = active ? __expf(bd1) : 0.f;
    float es0 = e0, es1 = e1;
#pragma unroll
    for (int m = 1; m < 16; m <<= 1) {
      es0 += __shfl_xor(es0, m, 16);
      es1 += __shfl_xor(es1, m, 16);
    }
    float c0 = e0 / es0;
    float c1 = e1 / es1;
#pragma unroll
    for (int d = 0; d < DIM_CAPS; ++d) {
      s0[d] += c0 * u0[d];
      s1[d] += c1 * u1[d];
    }
  }

  if (active) {
    float* sp0 = sbuf + (b0 * NUM_CAPS + n) * DIM_CAPS;
    float* sp1 = sbuf + ((b0 + 1) * NUM_CAPS + n) * DIM_CAPS;
#pragma unroll
    for (int d = 0; d < DIM_CAPS; ++d) {
      atomicAdd(&sp0[d], s0[d]);
      atomicAdd(&sp1[d], s1[d]);
    }
  }
}

// v = squash(s); V += v (routing) or out = v (final); re-zero s.
__global__ void vupdate_kernel(float* __restrict__ sbuf, float* __restrict__ Vbuf,
                               float* __restrict__ out, int is_final) {
  const int b   = blockIdx.x;            // 0..255
  const int t   = threadIdx.x;           // 0..159 : n = t/16, d = t%16
  const int idx = b * (NUM_CAPS * DIM_CAPS) + t;
  float s  = sbuf[idx];
  float sq = s * s;
#pragma unroll
  for (int m = 1; m < 16; m <<= 1) sq += __shfl_xor(sq, m, 16);  // sum over d
  float norm = sqrtf(sq);
  float v = s * (sq / (1.f + sq)) / (norm + 1e-8f);
  if (is_final) {
    out[idx] = v;
  } else {
    Vbuf[idx] += v;
    sbuf[idx] = 0.f;
  }
}

extern "C" void kernel_launch(void* const* d_in, const int* in_sizes, int n_in,
                              void* d_out, int out_size, void* d_ws, size_t ws_size,
                              hipStream_t stream) {
  const float* x = (const float*)d_in[0];  // [256,1152,8]
  const float* W = (const float*)d_in[1];  // [1,10,1152,16,8]
  float* out  = (float*)d_out;             // [256,10,16]
  float* sbuf = (float*)d_ws;                          // 40960 floats
  float* Vbuf = (float*)d_ws + B_TOT * NUM_CAPS * DIM_CAPS;  // 40960 floats

  // zero s and V (ws is poisoned 0xAA before every call)
  hipMemsetAsync(d_ws, 0, (size_t)2 * B_TOT * NUM_CAPS * DIM_CAPS * sizeof(float), stream);

  for (int p = 0; p < 4; ++p) {
    pass_kernel<<<dim3(B_TOT / B_BLK, IN_CAPS / I_T), 256, 0, stream>>>(x, W, Vbuf, sbuf);
    vupdate_kernel<<<B_TOT, NUM_CAPS * DIM_CAPS, 0, stream>>>(sbuf, Vbuf, out, p == 3);
  }
}

// Round 4
// 315.443 us; speedup vs baseline: 5.3742x; 4.0373x over previous
//
#include <hip/hip_runtime.h>

// Problem constants
#define IN_CAPS  1152
#define IN_DIM   8
#define NUM_CAPS 10
#define DIM_CAPS 16
#define B_TOT    256

#define I_T     12   // i's per block -> 96 i-tiles
#define N_TILES (IN_CAPS / I_T)   // 96
#define B_BLK   32   // batches per block; 2 per thread

// ws layout (floats):
//   Vbuf    [256][10][16]                = 40960
//   spart   [96][256][10][16]            = 3932160
//   Wt      [1152][16][2][16][4]         = 2359296  (n padded 10->16, zeros)
#define VBUF_F  (B_TOT * NUM_CAPS * DIM_CAPS)
#define SPART_F (N_TILES * B_TOT * NUM_CAPS * DIM_CAPS)
#define WT_F    (IN_CAPS * DIM_CAPS * 2 * 16 * 4)

// Transpose W[n][i][d][k8] -> Wt[i][d][h][n16][c4] so that per-(i,d,h) the
// 16 n-lanes read 16 contiguous float4s (2 fully-consumed cache lines per
// wave-instr instead of 16 scattered 147KB-apart lines).
__global__ __launch_bounds__(512) void transpose_kernel(
    const float* __restrict__ W, float* __restrict__ Wt) {
  const int i = blockIdx.x;          // 0..1151
  const int t = threadIdx.x;         // 0..511
  const int n = t & 15;
  const int h = (t >> 4) & 1;
  const int d = t >> 5;              // 0..15
  const float4* Wf4 = (const float4*)W;
  float4* Wtf4 = (float4*)Wt;
  float4 v = make_float4(0.f, 0.f, 0.f, 0.f);
  if (n < NUM_CAPS) v = Wf4[((size_t)(n * IN_CAPS + i) * DIM_CAPS + d) * 2 + h];
  // Wt float4-index: i*512 + d*32 + h*16 + n
  Wtf4[(size_t)i * 512 + d * 32 + h * 16 + n] = v;
}

// One routing sweep: recompute u_hat on the fly from Wt, softmax(u_hat.V)
// over n, store this block's partial s to its private tile slice (no atomics).
// NOTE: no min-waves in launch_bounds — live state is ~100 VGPRs; forcing 6
// waves/SIMD (R1) spilled to scratch and was 2x slower.
__global__ __launch_bounds__(256) void pass_kernel(
    const float* __restrict__ x, const float* __restrict__ Wt,
    const float* __restrict__ Vbuf, float* __restrict__ spart) {
  const int tid = threadIdx.x;
  const int n   = tid & 15;        // capsule slot (10 active of 16)
  const int g   = tid >> 4;        // 0..15 -> batch pair
  const int b0  = blockIdx.x * B_BLK + 2 * g;
  const int tile = blockIdx.y;
  const int i0  = tile * I_T;
  const bool active = (n < NUM_CAPS);
  const int nn = active ? n : 0;   // clamp for safe (wasted) V loads

  float V0[DIM_CAPS], V1[DIM_CAPS], s0[DIM_CAPS], s1[DIM_CAPS];
  const float* vp0 = Vbuf + (b0 * NUM_CAPS + nn) * DIM_CAPS;
  const float* vp1 = Vbuf + ((b0 + 1) * NUM_CAPS + nn) * DIM_CAPS;
#pragma unroll
  for (int d = 0; d < DIM_CAPS; ++d) {
    V0[d] = vp0[d]; V1[d] = vp1[d];
    s0[d] = 0.f;    s1[d] = 0.f;
  }

  const float4* __restrict__ Wtp = (const float4*)Wt;
  const float4* __restrict__ xp  = (const float4*)x;

  for (int i = i0; i < i0 + I_T; ++i) {
    // x[b,i,0:8] for the two batches (broadcast across the 16 n-lanes)
    float4 xa0 = xp[(size_t)(b0 * IN_CAPS + i) * 2];
    float4 xb0 = xp[(size_t)(b0 * IN_CAPS + i) * 2 + 1];
    float4 xa1 = xp[(size_t)((b0 + 1) * IN_CAPS + i) * 2];
    float4 xb1 = xp[(size_t)((b0 + 1) * IN_CAPS + i) * 2 + 1];

    // per-(i,d,h): lane n reads Wt float4 at i*512 + d*32 + h*16 + n
    const float4* wbase = Wtp + (size_t)i * 512 + n;

    float u0[DIM_CAPS], u1[DIM_CAPS];
    float bd0 = 0.f, bd1 = 0.f;
#pragma unroll
    for (int d = 0; d < DIM_CAPS; ++d) {
      float4 wa = wbase[d * 32];
      float4 wb = wbase[d * 32 + 16];
      float a = wa.x * xa0.x + wa.y * xa0.y + wa.z * xa0.z + wa.w * xa0.w
              + wb.x * xb0.x + wb.y * xb0.y + wb.z * xb0.z + wb.w * xb0.w;
      float c = wa.x * xa1.x + wa.y * xa1.y + wa.z * xa1.z + wa.w * xa1.w
              + wb.x * xb1.x + wb.y * xb1.y + wb.z * xb1.z + wb.w * xb1.w;
      u0[d] = a; u1[d] = c;
      bd0 += a * V0[d];
      bd1 += c * V1[d];
    }

    // softmax over n (10-wide; logits tiny so no max-subtraction needed)
    float e0 = active ? __expf(bd0) : 0.f;
    float e1 = active ? __expf(bd1) : 0.f;
    float es0 = e0, es1 = e1;
#pragma unroll
    for (int m = 1; m < 16; m <<= 1) {
      es0 += __shfl_xor(es0, m, 16);
      es1 += __shfl_xor(es1, m, 16);
    }
    float c0 = e0 / es0;
    float c1 = e1 / es1;
#pragma unroll
    for (int d = 0; d < DIM_CAPS; ++d) {
      s0[d] += c0 * u0[d];
      s1[d] += c1 * u1[d];
    }
  }

  if (active) {
    // private partial slice: spart[tile][b][n][d]
    float* sp0 = spart + ((size_t)(tile * B_TOT + b0) * NUM_CAPS + n) * DIM_CAPS;
    float* sp1 = spart + ((size_t)(tile * B_TOT + b0 + 1) * NUM_CAPS + n) * DIM_CAPS;
#pragma unroll
    for (int d = 0; d < DIM_CAPS; ++d) {
      sp0[d] = s0[d];
      sp1[d] = s1[d];
    }
  }
}

// Reduce 96 partial tiles -> s; v = squash(s); V += v (routing) or out = v.
__global__ void vupdate_kernel(const float* __restrict__ spart,
                               float* __restrict__ Vbuf,
                               float* __restrict__ out, int is_final) {
  const int b   = blockIdx.x;            // 0..255
  const int t   = threadIdx.x;           // 0..159 : n = t/16, d = t%16
  const int base = b * (NUM_CAPS * DIM_CAPS) + t;
  float s = 0.f;
#pragma unroll 8
  for (int tl = 0; tl < N_TILES; ++tl) {
    s += spart[(size_t)tl * (B_TOT * NUM_CAPS * DIM_CAPS) + base];
  }
  float sq = s * s;
#pragma unroll
  for (int m = 1; m < 16; m <<= 1) sq += __shfl_xor(sq, m, 16);  // sum over d
  float norm = sqrtf(sq);
  float v = s * (sq / (1.f + sq)) / (norm + 1e-8f);
  if (is_final) {
    out[base] = v;
  } else {
    Vbuf[base] += v;
  }
}

extern "C" void kernel_launch(void* const* d_in, const int* in_sizes, int n_in,
                              void* d_out, int out_size, void* d_ws, size_t ws_size,
                              hipStream_t stream) {
  const float* x = (const float*)d_in[0];  // [256,1152,8]
  const float* W = (const float*)d_in[1];  // [1,10,1152,16,8]
  float* out   = (float*)d_out;            // [256,10,16]
  float* Vbuf  = (float*)d_ws;
  float* spart = Vbuf + VBUF_F;
  float* Wt    = spart + SPART_F;

  // zero V only (spart is fully written each pass; Wt fully written below)
  hipMemsetAsync(Vbuf, 0, (size_t)VBUF_F * sizeof(float), stream);

  transpose_kernel<<<IN_CAPS, 512, 0, stream>>>(W, Wt);

  for (int p = 0; p < 4; ++p) {
    pass_kernel<<<dim3(B_TOT / B_BLK, N_TILES), 256, 0, stream>>>(x, Wt, Vbuf, spart);
    vupdate_kernel<<<B_TOT, NUM_CAPS * DIM_CAPS, 0, stream>>>(spart, Vbuf, out, p == 3);
  }
}

// Round 5
// 231.439 us; speedup vs baseline: 7.3249x; 1.3630x over previous
//
#include <hip/hip_runtime.h>
#include <hip/hip_bf16.h>

// Problem constants
#define IN_CAPS  1152
#define IN_DIM   8
#define NUM_CAPS 10
#define DIM_CAPS 16
#define B_TOT    256

// pre_kernel tiling (R3-proven shape)
#define I_T     12                 // i's per block -> 96 i-tiles
#define P_TILES (IN_CAPS / I_T)    // 96
#define B_BLK   32                 // batches per block; 2 per thread

// route_kernel tiling
#define I_S     9                  // i's per block -> 128 i-tiles
#define R_TILES (IN_CAPS / I_S)    // 128
#define RB_BLK  16                 // batches per block; 1 per thread

// ws layout (floats):
//   Vbuf  [256][10][16]                       = 40960
//   spart [128][256][10][16]                  = 5242880   (pre uses first 96 slices)
//   Wt    [1152][16][2][16][4]                = 2359296
//   ubuf  bf16 [256][1152][10][16]            = 47185920 bf16 = 23592960 float-slots
#define VBUF_F  (B_TOT * NUM_CAPS * DIM_CAPS)
#define SPART_F (R_TILES * B_TOT * NUM_CAPS * DIM_CAPS)
#define WT_F    (IN_CAPS * DIM_CAPS * 2 * 16 * 4)

__device__ __forceinline__ unsigned pack2_bf16(float a, float b) {
  __hip_bfloat162 h = __float22bfloat162_rn(make_float2(a, b));
  return *reinterpret_cast<unsigned*>(&h);
}
__device__ __forceinline__ void unpack2_bf16(unsigned w, float& lo, float& hi) {
  lo = __uint_as_float(w << 16);
  hi = __uint_as_float(w & 0xffff0000u);
}

// Transpose W[n][i][d][k8] -> Wt[i][d][h][n16][c4]: per-(i,d,h) the 16 n-lanes
// read 16 contiguous float4s (2 fully-consumed lines/wave-instr).
__global__ __launch_bounds__(512) void transpose_kernel(
    const float* __restrict__ W, float* __restrict__ Wt) {
  const int i = blockIdx.x;
  const int t = threadIdx.x;
  const int n = t & 15;
  const int h = (t >> 4) & 1;
  const int d = t >> 5;
  const float4* Wf4 = (const float4*)W;
  float4* Wtf4 = (float4*)Wt;
  float4 v = make_float4(0.f, 0.f, 0.f, 0.f);
  if (n < NUM_CAPS) v = Wf4[((size_t)(n * IN_CAPS + i) * DIM_CAPS + d) * 2 + h];
  Wtf4[(size_t)i * 512 + d * 32 + h * 16 + n] = v;
}

// Compute u_hat once; write bf16 ubuf; fuse routing pass 0 (V=0 -> c = 1/10
// exactly, so s = 0.1 * sum_i u). No softmax needed here.
// NOTE: no min-waves in launch_bounds — R1 showed forced occupancy spills.
__global__ __launch_bounds__(256) void pre_kernel(
    const float* __restrict__ x, const float* __restrict__ Wt,
    uint4* __restrict__ ubuf, float* __restrict__ spart) {
  const int tid = threadIdx.x;
  const int n   = tid & 15;
  const int g   = tid >> 4;
  const int b0  = blockIdx.x * B_BLK + 2 * g;
  const int tile = blockIdx.y;
  const int i0  = tile * I_T;
  const bool active = (n < NUM_CAPS);

  float s0[DIM_CAPS], s1[DIM_CAPS];
#pragma unroll
  for (int d = 0; d < DIM_CAPS; ++d) { s0[d] = 0.f; s1[d] = 0.f; }

  const float4* __restrict__ Wtp = (const float4*)Wt;
  const float4* __restrict__ xp  = (const float4*)x;

  for (int i = i0; i < i0 + I_T; ++i) {
    float4 xa0 = xp[(size_t)(b0 * IN_CAPS + i) * 2];
    float4 xb0 = xp[(size_t)(b0 * IN_CAPS + i) * 2 + 1];
    float4 xa1 = xp[(size_t)((b0 + 1) * IN_CAPS + i) * 2];
    float4 xb1 = xp[(size_t)((b0 + 1) * IN_CAPS + i) * 2 + 1];

    const float4* wbase = Wtp + (size_t)i * 512 + n;

    float u0[DIM_CAPS], u1[DIM_CAPS];
#pragma unroll
    for (int d = 0; d < DIM_CAPS; ++d) {
      float4 wa = wbase[d * 32];
      float4 wb = wbase[d * 32 + 16];
      u0[d] = wa.x * xa0.x + wa.y * xa0.y + wa.z * xa0.z + wa.w * xa0.w
            + wb.x * xb0.x + wb.y * xb0.y + wb.z * xb0.z + wb.w * xb0.w;
      u1[d] = wa.x * xa1.x + wa.y * xa1.y + wa.z * xa1.z + wa.w * xa1.w
            + wb.x * xb1.x + wb.y * xb1.y + wb.z * xb1.z + wb.w * xb1.w;
      s0[d] += u0[d];
      s1[d] += u1[d];
    }

    if (active) {
      // ubuf element index: ((b*1152 + i)*10 + n) * 16 bf16 = *2 uint4
      size_t ub0 = ((size_t)(b0 * IN_CAPS + i) * NUM_CAPS + n) * 2;
      size_t ub1 = ((size_t)((b0 + 1) * IN_CAPS + i) * NUM_CAPS + n) * 2;
      uint4 p0, p1;
      p0.x = pack2_bf16(u0[0], u0[1]);  p0.y = pack2_bf16(u0[2], u0[3]);
      p0.z = pack2_bf16(u0[4], u0[5]);  p0.w = pack2_bf16(u0[6], u0[7]);
      p1.x = pack2_bf16(u0[8], u0[9]);  p1.y = pack2_bf16(u0[10], u0[11]);
      p1.z = pack2_bf16(u0[12], u0[13]); p1.w = pack2_bf16(u0[14], u0[15]);
      ubuf[ub0] = p0; ubuf[ub0 + 1] = p1;
      p0.x = pack2_bf16(u1[0], u1[1]);  p0.y = pack2_bf16(u1[2], u1[3]);
      p0.z = pack2_bf16(u1[4], u1[5]);  p0.w = pack2_bf16(u1[6], u1[7]);
      p1.x = pack2_bf16(u1[8], u1[9]);  p1.y = pack2_bf16(u1[10], u1[11]);
      p1.z = pack2_bf16(u1[12], u1[13]); p1.w = pack2_bf16(u1[14], u1[15]);
      ubuf[ub1] = p0; ubuf[ub1 + 1] = p1;
    }
  }

  if (active) {
    float* sp0 = spart + ((size_t)(tile * B_TOT + b0) * NUM_CAPS + n) * DIM_CAPS;
    float* sp1 = spart + ((size_t)(tile * B_TOT + b0 + 1) * NUM_CAPS + n) * DIM_CAPS;
#pragma unroll
    for (int d = 0; d < DIM_CAPS; ++d) {
      sp0[d] = 0.1f * s0[d];
      sp1[d] = 0.1f * s1[d];
    }
  }
}

// One routing sweep over materialized bf16 u_hat: bd = u.V, softmax over n,
// s += c*u, partial store (no atomics). 1 batch/thread, small state.
__global__ __launch_bounds__(256) void route_kernel(
    const uint4* __restrict__ ubuf, const float* __restrict__ Vbuf,
    float* __restrict__ spart) {
  const int tid = threadIdx.x;
  const int n   = tid & 15;
  const int bl  = tid >> 4;
  const int b   = blockIdx.x * RB_BLK + bl;
  const int tile = blockIdx.y;
  const int i0  = tile * I_S;
  const bool active = (n < NUM_CAPS);
  const int nn = active ? n : 0;

  float V[DIM_CAPS], s[DIM_CAPS];
  const float* vp = Vbuf + (b * NUM_CAPS + nn) * DIM_CAPS;
#pragma unroll
  for (int d = 0; d < DIM_CAPS; ++d) { V[d] = vp[d]; s[d] = 0.f; }

  for (int i = i0; i < i0 + I_S; ++i) {
    const uint4* up = ubuf + ((size_t)(b * IN_CAPS + i) * NUM_CAPS + nn) * 2;
    uint4 w0 = up[0];
    uint4 w1 = up[1];
    float u[DIM_CAPS];
    unpack2_bf16(w0.x, u[0], u[1]);   unpack2_bf16(w0.y, u[2], u[3]);
    unpack2_bf16(w0.z, u[4], u[5]);   unpack2_bf16(w0.w, u[6], u[7]);
    unpack2_bf16(w1.x, u[8], u[9]);   unpack2_bf16(w1.y, u[10], u[11]);
    unpack2_bf16(w1.z, u[12], u[13]); unpack2_bf16(w1.w, u[14], u[15]);

    float bd = 0.f;
#pragma unroll
    for (int d = 0; d < DIM_CAPS; ++d) bd += u[d] * V[d];

    float e = active ? __expf(bd) : 0.f;
    float es = e;
#pragma unroll
    for (int m = 1; m < 16; m <<= 1) es += __shfl_xor(es, m, 16);
    float c = e / es;
#pragma unroll
    for (int d = 0; d < DIM_CAPS; ++d) s[d] += c * u[d];
  }

  if (active) {
    float* sp = spart + ((size_t)(tile * B_TOT + b) * NUM_CAPS + n) * DIM_CAPS;
#pragma unroll
    for (int d = 0; d < DIM_CAPS; ++d) sp[d] = s[d];
  }
}

// Reduce ntiles partial tiles -> s; v = squash(s); V += v or out = v.
__global__ void vupdate_kernel(const float* __restrict__ spart,
                               float* __restrict__ Vbuf,
                               float* __restrict__ out, int ntiles, int is_final) {
  const int b   = blockIdx.x;            // 0..255
  const int t   = threadIdx.x;           // 0..159 : n = t/16, d = t%16
  const int base = b * (NUM_CAPS * DIM_CAPS) + t;
  float s = 0.f;
#pragma unroll 4
  for (int tl = 0; tl < ntiles; ++tl) {
    s += spart[(size_t)tl * (B_TOT * NUM_CAPS * DIM_CAPS) + base];
  }
  float sq = s * s;
#pragma unroll
  for (int m = 1; m < 16; m <<= 1) sq += __shfl_xor(sq, m, 16);  // sum over d
  float norm = sqrtf(sq);
  float v = s * (sq / (1.f + sq)) / (norm + 1e-8f);
  if (is_final) {
    out[base] = v;
  } else {
    Vbuf[base] += v;
  }
}

extern "C" void kernel_launch(void* const* d_in, const int* in_sizes, int n_in,
                              void* d_out, int out_size, void* d_ws, size_t ws_size,
                              hipStream_t stream) {
  const float* x = (const float*)d_in[0];  // [256,1152,8]
  const float* W = (const float*)d_in[1];  // [1,10,1152,16,8]
  float* out   = (float*)d_out;            // [256,10,16]
  float* Vbuf  = (float*)d_ws;
  float* spart = Vbuf + VBUF_F;
  float* Wt    = spart + SPART_F;
  uint4* ubuf  = (uint4*)(Wt + WT_F);      // 94.4 MB bf16 u_hat

  // zero V only (spart/ubuf fully written before use)
  hipMemsetAsync(Vbuf, 0, (size_t)VBUF_F * sizeof(float), stream);

  transpose_kernel<<<IN_CAPS, 512, 0, stream>>>(W, Wt);

  // pass 0 fused into u_hat materialization (c == 0.1 exactly when V == 0)
  pre_kernel<<<dim3(B_TOT / B_BLK, P_TILES), 256, 0, stream>>>(x, Wt, ubuf, spart);
  vupdate_kernel<<<B_TOT, NUM_CAPS * DIM_CAPS, 0, stream>>>(spart, Vbuf, out, P_TILES, 0);

  // passes 1..3 stream bf16 u_hat
  for (int p = 1; p < 4; ++p) {
    route_kernel<<<dim3(B_TOT / RB_BLK, R_TILES), 256, 0, stream>>>(ubuf, Vbuf, spart);
    vupdate_kernel<<<B_TOT, NUM_CAPS * DIM_CAPS, 0, stream>>>(spart, Vbuf, out, R_TILES, p == 3);
  }
}

// Round 6
// 209.460 us; speedup vs baseline: 8.0935x; 1.1049x over previous
//
#include <hip/hip_runtime.h>
#include <hip/hip_bf16.h>

// Problem constants
#define IN_CAPS  1152
#define IN_DIM   8
#define NUM_CAPS 10
#define DIM_CAPS 16
#define B_TOT    256

// pre_kernel tiling: more blocks for latency hiding (R4: 768 blocks -> 27% occ)
#define I_T     6                  // i's per block -> 192 i-tiles
#define P_TILES (IN_CAPS / I_T)    // 192
#define B_BLK   32                 // batches per block; 2 per thread

// route_kernel tiling
#define I_S     9                  // i's per block -> 128 i-tiles
#define R_TILES (IN_CAPS / I_S)    // 128
#define RB_BLK  16                 // batches per block; 1 per thread

// ws layout (floats):
//   Vbuf  [256][10][16]            = 40960
//   spart [192][256][10][16]       = 7864320
//   Wt    [1152][16][2][16][4]     = 2359296
//   ubuf  bf16 [256][1152][10][16] = 47185920 bf16 = 23592960 float-slots
//   total ~135.4 MB
#define VBUF_F  (B_TOT * NUM_CAPS * DIM_CAPS)
#define SPART_F (P_TILES * B_TOT * NUM_CAPS * DIM_CAPS)
#define WT_F    (IN_CAPS * DIM_CAPS * 2 * 16 * 4)

typedef float v2f __attribute__((ext_vector_type(2)));

__device__ __forceinline__ unsigned pack2_bf16(float a, float b) {
  __hip_bfloat162 h = __float22bfloat162_rn(make_float2(a, b));
  return *reinterpret_cast<unsigned*>(&h);
}
__device__ __forceinline__ v2f unpack2_bf16_v(unsigned w) {
  v2f r;
  r.x = __uint_as_float(w << 16);
  r.y = __uint_as_float(w & 0xffff0000u);
  return r;
}

// Transpose W[n][i][d][k8] -> Wt[i][d][h][n16][c4]: per-(i,d,h) the 16 n-lanes
// read 16 contiguous float4s (2 fully-consumed lines/wave-instr).
__global__ __launch_bounds__(512) void transpose_kernel(
    const float* __restrict__ W, float* __restrict__ Wt) {
  const int i = blockIdx.x;
  const int t = threadIdx.x;
  const int n = t & 15;
  const int h = (t >> 4) & 1;
  const int d = t >> 5;
  const float4* Wf4 = (const float4*)W;
  float4* Wtf4 = (float4*)Wt;
  float4 v = make_float4(0.f, 0.f, 0.f, 0.f);
  if (n < NUM_CAPS) v = Wf4[((size_t)(n * IN_CAPS + i) * DIM_CAPS + d) * 2 + h];
  Wtf4[(size_t)i * 512 + d * 32 + h * 16 + n] = v;
}

// Compute u_hat once (packed f32: both batches of the pair in one v2f lane),
// write bf16 ubuf; fuse routing pass 0 (V=0 -> c = 1/10 exactly).
// NOTE: no min-waves in launch_bounds — R1 showed forced occupancy spills.
__global__ __launch_bounds__(256) void pre_kernel(
    const float* __restrict__ x, const float* __restrict__ Wt,
    uint4* __restrict__ ubuf, float* __restrict__ spart) {
  const int tid = threadIdx.x;
  const int n   = tid & 15;
  const int g   = tid >> 4;
  const int b0  = blockIdx.x * B_BLK + 2 * g;
  const int tile = blockIdx.y;
  const int i0  = tile * I_T;
  const bool active = (n < NUM_CAPS);

  v2f s01[DIM_CAPS];
#pragma unroll
  for (int d = 0; d < DIM_CAPS; ++d) s01[d] = (v2f)(0.f);

  const float4* __restrict__ Wtp = (const float4*)Wt;
  const float4* __restrict__ xp  = (const float4*)x;

  for (int i = i0; i < i0 + I_T; ++i) {
    float4 xa0 = xp[(size_t)(b0 * IN_CAPS + i) * 2];
    float4 xb0 = xp[(size_t)(b0 * IN_CAPS + i) * 2 + 1];
    float4 xa1 = xp[(size_t)((b0 + 1) * IN_CAPS + i) * 2];
    float4 xb1 = xp[(size_t)((b0 + 1) * IN_CAPS + i) * 2 + 1];
    v2f xx[8];
    xx[0].x = xa0.x; xx[0].y = xa1.x;  xx[1].x = xa0.y; xx[1].y = xa1.y;
    xx[2].x = xa0.z; xx[2].y = xa1.z;  xx[3].x = xa0.w; xx[3].y = xa1.w;
    xx[4].x = xb0.x; xx[4].y = xb1.x;  xx[5].x = xb0.y; xx[5].y = xb1.y;
    xx[6].x = xb0.z; xx[6].y = xb1.z;  xx[7].x = xb0.w; xx[7].y = xb1.w;

    const float4* wbase = Wtp + (size_t)i * 512 + n;

    v2f u01[DIM_CAPS];
#pragma unroll
    for (int d = 0; d < DIM_CAPS; ++d) {
      float4 wa = wbase[d * 32];
      float4 wb = wbase[d * 32 + 16];
      v2f u = wa.x * xx[0] + wa.y * xx[1] + wa.z * xx[2] + wa.w * xx[3]
            + wb.x * xx[4] + wb.y * xx[5] + wb.z * xx[6] + wb.w * xx[7];
      u01[d] = u;
      s01[d] += u;
    }

    if (active) {
      size_t ub0 = ((size_t)(b0 * IN_CAPS + i) * NUM_CAPS + n) * 2;
      size_t ub1 = ((size_t)((b0 + 1) * IN_CAPS + i) * NUM_CAPS + n) * 2;
      uint4 p0, p1;
      p0.x = pack2_bf16(u01[0].x, u01[1].x);   p0.y = pack2_bf16(u01[2].x, u01[3].x);
      p0.z = pack2_bf16(u01[4].x, u01[5].x);   p0.w = pack2_bf16(u01[6].x, u01[7].x);
      p1.x = pack2_bf16(u01[8].x, u01[9].x);   p1.y = pack2_bf16(u01[10].x, u01[11].x);
      p1.z = pack2_bf16(u01[12].x, u01[13].x); p1.w = pack2_bf16(u01[14].x, u01[15].x);
      ubuf[ub0] = p0; ubuf[ub0 + 1] = p1;
      p0.x = pack2_bf16(u01[0].y, u01[1].y);   p0.y = pack2_bf16(u01[2].y, u01[3].y);
      p0.z = pack2_bf16(u01[4].y, u01[5].y);   p0.w = pack2_bf16(u01[6].y, u01[7].y);
      p1.x = pack2_bf16(u01[8].y, u01[9].y);   p1.y = pack2_bf16(u01[10].y, u01[11].y);
      p1.z = pack2_bf16(u01[12].y, u01[13].y); p1.w = pack2_bf16(u01[14].y, u01[15].y);
      ubuf[ub1] = p0; ubuf[ub1 + 1] = p1;
    }
  }

  if (active) {
    float* sp0 = spart + ((size_t)(tile * B_TOT + b0) * NUM_CAPS + n) * DIM_CAPS;
    float* sp1 = spart + ((size_t)(tile * B_TOT + b0 + 1) * NUM_CAPS + n) * DIM_CAPS;
#pragma unroll
    for (int d = 0; d < DIM_CAPS; ++d) {
      sp0[d] = 0.1f * s01[d].x;
      sp1[d] = 0.1f * s01[d].y;
    }
  }
}

// One routing sweep over materialized bf16 u_hat, packed-f32 math:
// bd = u.V, softmax over n, s += c*u, partial store (no atomics).
__global__ __launch_bounds__(256) void route_kernel(
    const uint4* __restrict__ ubuf, const float* __restrict__ Vbuf,
    float* __restrict__ spart) {
  const int tid = threadIdx.x;
  const int n   = tid & 15;
  const int bl  = tid >> 4;
  const int b   = blockIdx.x * RB_BLK + bl;
  const int tile = blockIdx.y;
  const int i0  = tile * I_S;
  const bool active = (n < NUM_CAPS);
  const int nn = active ? n : 0;

  v2f V2[8], s2[8];
  const v2f* vp = (const v2f*)(Vbuf + (b * NUM_CAPS + nn) * DIM_CAPS);
#pragma unroll
  for (int j = 0; j < 8; ++j) { V2[j] = vp[j]; s2[j] = (v2f)(0.f); }

  for (int i = i0; i < i0 + I_S; ++i) {
    const uint4* up = ubuf + ((size_t)(b * IN_CAPS + i) * NUM_CAPS + nn) * 2;
    uint4 w0 = up[0];
    uint4 w1 = up[1];
    v2f u2[8];
    u2[0] = unpack2_bf16_v(w0.x); u2[1] = unpack2_bf16_v(w0.y);
    u2[2] = unpack2_bf16_v(w0.z); u2[3] = unpack2_bf16_v(w0.w);
    u2[4] = unpack2_bf16_v(w1.x); u2[5] = unpack2_bf16_v(w1.y);
    u2[6] = unpack2_bf16_v(w1.z); u2[7] = unpack2_bf16_v(w1.w);

    v2f acc = u2[0] * V2[0];
#pragma unroll
    for (int j = 1; j < 8; ++j) acc += u2[j] * V2[j];
    float bd = acc.x + acc.y;

    float e = active ? __expf(bd) : 0.f;
    float es = e;
#pragma unroll
    for (int m = 1; m < 16; m <<= 1) es += __shfl_xor(es, m, 16);
    float c = e / es;
#pragma unroll
    for (int j = 0; j < 8; ++j) s2[j] += c * u2[j];
  }

  if (active) {
    v2f* sp = (v2f*)(spart + ((size_t)(tile * B_TOT + b) * NUM_CAPS + n) * DIM_CAPS);
#pragma unroll
    for (int j = 0; j < 8; ++j) sp[j] = s2[j];
  }
}

// Reduce NT partial tiles -> s; v = squash(s); V += v or out = v.
template <int NT>
__global__ void vupdate_kernel(const float* __restrict__ spart,
                               float* __restrict__ Vbuf,
                               float* __restrict__ out, int is_final) {
  const int b   = blockIdx.x;            // 0..255
  const int t   = threadIdx.x;           // 0..159 : n = t/16, d = t%16
  const int base = b * (NUM_CAPS * DIM_CAPS) + t;
  float s = 0.f;
#pragma unroll 16
  for (int tl = 0; tl < NT; ++tl) {
    s += spart[(size_t)tl * (B_TOT * NUM_CAPS * DIM_CAPS) + base];
  }
  float sq = s * s;
#pragma unroll
  for (int m = 1; m < 16; m <<= 1) sq += __shfl_xor(sq, m, 16);  // sum over d
  float norm = sqrtf(sq);
  float v = s * (sq / (1.f + sq)) / (norm + 1e-8f);
  if (is_final) {
    out[base] = v;
  } else {
    Vbuf[base] += v;
  }
}

extern "C" void kernel_launch(void* const* d_in, const int* in_sizes, int n_in,
                              void* d_out, int out_size, void* d_ws, size_t ws_size,
                              hipStream_t stream) {
  const float* x = (const float*)d_in[0];  // [256,1152,8]
  const float* W = (const float*)d_in[1];  // [1,10,1152,16,8]
  float* out   = (float*)d_out;            // [256,10,16]
  float* Vbuf  = (float*)d_ws;
  float* spart = Vbuf + VBUF_F;
  float* Wt    = spart + SPART_F;
  uint4* ubuf  = (uint4*)(Wt + WT_F);      // 94.4 MB bf16 u_hat

  // zero V only (spart/ubuf fully written before use)
  hipMemsetAsync(Vbuf, 0, (size_t)VBUF_F * sizeof(float), stream);

  transpose_kernel<<<IN_CAPS, 512, 0, stream>>>(W, Wt);

  // pass 0 fused into u_hat materialization (c == 0.1 exactly when V == 0)
  pre_kernel<<<dim3(B_TOT / B_BLK, P_TILES), 256, 0, stream>>>(x, Wt, ubuf, spart);
  vupdate_kernel<P_TILES><<<B_TOT, NUM_CAPS * DIM_CAPS, 0, stream>>>(spart, Vbuf, out, 0);

  // passes 1..3 stream bf16 u_hat
  for (int p = 1; p < 4; ++p) {
    route_kernel<<<dim3(B_TOT / RB_BLK, R_TILES), 256, 0, stream>>>(ubuf, Vbuf, spart);
    vupdate_kernel<R_TILES><<<B_TOT, NUM_CAPS * DIM_CAPS, 0, stream>>>(spart, Vbuf, out, p == 3);
  }
}

// Round 8
// 198.633 us; speedup vs baseline: 8.5347x; 1.0545x over previous
//
#include <hip/hip_runtime.h>
#include <hip/hip_bf16.h>

// Problem constants
#define IN_CAPS  1152
#define IN_DIM   8
#define NUM_CAPS 10
#define DIM_CAPS 16
#define B_TOT    256

// pre_kernel tiling (R4-proven: 768 blocks, 62 us)
#define I_T     12                 // i's per block -> 96 i-tiles
#define P_TILES (IN_CAPS / I_T)    // 96
#define B_BLK   32                 // batches per block; 2 per thread

// route_kernel tiling
#define I_S     12                 // i's per block -> 96 i-tiles
#define R_TILES (IN_CAPS / I_S)    // 96
#define RB_BLK  16                 // batches per block; 1 per thread

// ws layout (floats):
//   Vbuf  [256][10][16]            = 40960
//   spart [96][256][10][16]        = 3932160
//   Wt    [1152][16][2][16][4]     = 2359296
//   ubuf  bf16 [256][1152][10][16] = 47185920 bf16 = 23592960 float-slots
//   total ~120 MB
#define VBUF_F  (B_TOT * NUM_CAPS * DIM_CAPS)
#define SPART_F (P_TILES * B_TOT * NUM_CAPS * DIM_CAPS)
#define WT_F    (IN_CAPS * DIM_CAPS * 2 * 16 * 4)

typedef float v2f __attribute__((ext_vector_type(2)));

__device__ __forceinline__ unsigned pack2_bf16(float a, float b) {
  __hip_bfloat162 h = __float22bfloat162_rn(make_float2(a, b));
  return *reinterpret_cast<unsigned*>(&h);
}
__device__ __forceinline__ v2f unpack2_bf16_v(unsigned w) {
  v2f r;
  r.x = __uint_as_float(w << 16);
  r.y = __uint_as_float(w & 0xffff0000u);
  return r;
}

// Transpose W[n][i][d][k8] -> Wt[i][d][h][n16][c4]: per-(i,d,h) the 16 n-lanes
// read 16 contiguous float4s (2 fully-consumed lines/wave-instr).
__global__ __launch_bounds__(512) void transpose_kernel(
    const float* __restrict__ W, float* __restrict__ Wt) {
  const int i = blockIdx.x;
  const int t = threadIdx.x;
  const int n = t & 15;
  const int h = (t >> 4) & 1;
  const int d = t >> 5;
  const float4* Wf4 = (const float4*)W;
  float4* Wtf4 = (float4*)Wt;
  float4 v = make_float4(0.f, 0.f, 0.f, 0.f);
  if (n < NUM_CAPS) v = Wf4[((size_t)(n * IN_CAPS + i) * DIM_CAPS + d) * 2 + h];
  Wtf4[(size_t)i * 512 + d * 32 + h * 16 + n] = v;
}

// Compute u_hat once; write bf16 ubuf; fuse routing pass 0 (V=0 -> c = 1/10
// exactly, so s = 0.1 * sum_i u). R4-exact structure (62 us measured).
// NOTE: no min-waves in launch_bounds — R1 showed forced occupancy spills.
__global__ __launch_bounds__(256) void pre_kernel(
    const float* __restrict__ x, const float* __restrict__ Wt,
    uint4* __restrict__ ubuf, float* __restrict__ spart) {
  const int tid = threadIdx.x;
  const int n   = tid & 15;
  const int g   = tid >> 4;
  const int b0  = blockIdx.x * B_BLK + 2 * g;
  const int tile = blockIdx.y;
  const int i0  = tile * I_T;
  const bool active = (n < NUM_CAPS);

  float s0[DIM_CAPS], s1[DIM_CAPS];
#pragma unroll
  for (int d = 0; d < DIM_CAPS; ++d) { s0[d] = 0.f; s1[d] = 0.f; }

  const float4* __restrict__ Wtp = (const float4*)Wt;
  const float4* __restrict__ xp  = (const float4*)x;

  for (int i = i0; i < i0 + I_T; ++i) {
    float4 xa0 = xp[(size_t)(b0 * IN_CAPS + i) * 2];
    float4 xb0 = xp[(size_t)(b0 * IN_CAPS + i) * 2 + 1];
    float4 xa1 = xp[(size_t)((b0 + 1) * IN_CAPS + i) * 2];
    float4 xb1 = xp[(size_t)((b0 + 1) * IN_CAPS + i) * 2 + 1];

    const float4* wbase = Wtp + (size_t)i * 512 + n;

    float u0[DIM_CAPS], u1[DIM_CAPS];
#pragma unroll
    for (int d = 0; d < DIM_CAPS; ++d) {
      float4 wa = wbase[d * 32];
      float4 wb = wbase[d * 32 + 16];
      u0[d] = wa.x * xa0.x + wa.y * xa0.y + wa.z * xa0.z + wa.w * xa0.w
            + wb.x * xb0.x + wb.y * xb0.y + wb.z * xb0.z + wb.w * xb0.w;
      u1[d] = wa.x * xa1.x + wa.y * xa1.y + wa.z * xa1.z + wa.w * xa1.w
            + wb.x * xb1.x + wb.y * xb1.y + wb.z * xb1.z + wb.w * xb1.w;
      s0[d] += u0[d];
      s1[d] += u1[d];
    }

    if (active) {
      // ubuf element index: ((b*1152 + i)*10 + n) * 16 bf16 = *2 uint4
      size_t ub0 = ((size_t)(b0 * IN_CAPS + i) * NUM_CAPS + n) * 2;
      size_t ub1 = ((size_t)((b0 + 1) * IN_CAPS + i) * NUM_CAPS + n) * 2;
      uint4 p0, p1;
      p0.x = pack2_bf16(u0[0], u0[1]);  p0.y = pack2_bf16(u0[2], u0[3]);
      p0.z = pack2_bf16(u0[4], u0[5]);  p0.w = pack2_bf16(u0[6], u0[7]);
      p1.x = pack2_bf16(u0[8], u0[9]);  p1.y = pack2_bf16(u0[10], u0[11]);
      p1.z = pack2_bf16(u0[12], u0[13]); p1.w = pack2_bf16(u0[14], u0[15]);
      ubuf[ub0] = p0; ubuf[ub0 + 1] = p1;
      p0.x = pack2_bf16(u1[0], u1[1]);  p0.y = pack2_bf16(u1[2], u1[3]);
      p0.z = pack2_bf16(u1[4], u1[5]);  p0.w = pack2_bf16(u1[6], u1[7]);
      p1.x = pack2_bf16(u1[8], u1[9]);  p1.y = pack2_bf16(u1[10], u1[11]);
      p1.z = pack2_bf16(u1[12], u1[13]); p1.w = pack2_bf16(u1[14], u1[15]);
      ubuf[ub1] = p0; ubuf[ub1 + 1] = p1;
    }
  }

  if (active) {
    float* sp0 = spart + ((size_t)(tile * B_TOT + b0) * NUM_CAPS + n) * DIM_CAPS;
    float* sp1 = spart + ((size_t)(tile * B_TOT + b0 + 1) * NUM_CAPS + n) * DIM_CAPS;
#pragma unroll
    for (int d = 0; d < DIM_CAPS; ++d) {
      sp0[d] = 0.1f * s0[d];
      sp1[d] = 0.1f * s1[d];
    }
  }
}

// One routing sweep over materialized bf16 u_hat, software-pipelined:
// prefetch i+1's loads during i's compute. bd = u.V, softmax over n,
// s += c*u, partial store (no atomics).
__global__ __launch_bounds__(256) void route_kernel(
    const uint4* __restrict__ ubuf, const float* __restrict__ Vbuf,
    float* __restrict__ spart) {
  const int tid = threadIdx.x;
  const int n   = tid & 15;
  const int bl  = tid >> 4;
  const int b   = blockIdx.x * RB_BLK + bl;
  const int tile = blockIdx.y;
  const int i0  = tile * I_S;
  const bool active = (n < NUM_CAPS);
  const int nn = active ? n : 0;

  v2f V2[8], s2[8];
  const v2f* vp = (const v2f*)(Vbuf + (b * NUM_CAPS + nn) * DIM_CAPS);
#pragma unroll
  for (int j = 0; j < 8; ++j) { V2[j] = vp[j]; s2[j] = (v2f)(0.f); }

  // base of this thread's i-run; stride per i = NUM_CAPS*2 uint4
  const uint4* up = ubuf + ((size_t)(b * IN_CAPS + i0) * NUM_CAPS + nn) * 2;
  uint4 w0 = up[0];
  uint4 w1 = up[1];

#pragma unroll
  for (int ii = 0; ii < I_S; ++ii) {
    // prefetch next i (clamped -> always valid, redundant on last iter)
    const int nxt = (ii + 1 < I_S) ? (ii + 1) : ii;
    const uint4* upn = up + (size_t)nxt * (NUM_CAPS * 2);
    uint4 p0 = upn[0];
    uint4 p1 = upn[1];

    v2f u2[8];
    u2[0] = unpack2_bf16_v(w0.x); u2[1] = unpack2_bf16_v(w0.y);
    u2[2] = unpack2_bf16_v(w0.z); u2[3] = unpack2_bf16_v(w0.w);
    u2[4] = unpack2_bf16_v(w1.x); u2[5] = unpack2_bf16_v(w1.y);
    u2[6] = unpack2_bf16_v(w1.z); u2[7] = unpack2_bf16_v(w1.w);

    v2f acc = u2[0] * V2[0];
#pragma unroll
    for (int j = 1; j < 8; ++j) acc += u2[j] * V2[j];
    float bd = acc.x + acc.y;

    float e = active ? __expf(bd) : 0.f;
    float es = e;
#pragma unroll
    for (int m = 1; m < 16; m <<= 1) es += __shfl_xor(es, m, 16);
    float c = e / es;
#pragma unroll
    for (int j = 0; j < 8; ++j) s2[j] += c * u2[j];

    w0 = p0; w1 = p1;
  }

  if (active) {
    v2f* sp = (v2f*)(spart + ((size_t)(tile * B_TOT + b) * NUM_CAPS + n) * DIM_CAPS);
#pragma unroll
    for (int j = 0; j < 8; ++j) sp[j] = s2[j];
  }
}

// Reduce NT partial tiles -> s; v = squash(s); V += v or out = v.
template <int NT>
__global__ void vupdate_kernel(const float* __restrict__ spart,
                               float* __restrict__ Vbuf,
                               float* __restrict__ out, int is_final) {
  const int b   = blockIdx.x;            // 0..255
  const int t   = threadIdx.x;           // 0..159 : n = t/16, d = t%16
  const int base = b * (NUM_CAPS * DIM_CAPS) + t;
  float s = 0.f;
#pragma unroll 16
  for (int tl = 0; tl < NT; ++tl) {
    s += spart[(size_t)tl * (B_TOT * NUM_CAPS * DIM_CAPS) + base];
  }
  float sq = s * s;
#pragma unroll
  for (int m = 1; m < 16; m <<= 1) sq += __shfl_xor(sq, m, 16);  // sum over d
  float norm = sqrtf(sq);
  float v = s * (sq / (1.f + sq)) / (norm + 1e-8f);
  if (is_final) {
    out[base] = v;
  } else {
    Vbuf[base] += v;
  }
}

extern "C" void kernel_launch(void* const* d_in, const int* in_sizes, int n_in,
                              void* d_out, int out_size, void* d_ws, size_t ws_size,
                              hipStream_t stream) {
  const float* x = (const float*)d_in[0];  // [256,1152,8]
  const float* W = (const float*)d_in[1];  // [1,10,1152,16,8]
  float* out   = (float*)d_out;            // [256,10,16]
  float* Vbuf  = (float*)d_ws;
  float* spart = Vbuf + VBUF_F;
  float* Wt    = spart + SPART_F;
  uint4* ubuf  = (uint4*)(Wt + WT_F);      // 94.4 MB bf16 u_hat

  // zero V only (spart/ubuf fully written before use)
  hipMemsetAsync(Vbuf, 0, (size_t)VBUF_F * sizeof(float), stream);

  transpose_kernel<<<IN_CAPS, 512, 0, stream>>>(W, Wt);

  // pass 0 fused into u_hat materialization (c == 0.1 exactly when V == 0)
  pre_kernel<<<dim3(B_TOT / B_BLK, P_TILES), 256, 0, stream>>>(x, Wt, ubuf, spart);
  vupdate_kernel<P_TILES><<<B_TOT, NUM_CAPS * DIM_CAPS, 0, stream>>>(spart, Vbuf, out, 0);

  // passes 1..3 stream bf16 u_hat
  for (int p = 1; p < 4; ++p) {
    route_kernel<<<dim3(B_TOT / RB_BLK, R_TILES), 256, 0, stream>>>(ubuf, Vbuf, spart);
    vupdate_kernel<R_TILES><<<B_TOT, NUM_CAPS * DIM_CAPS, 0, stream>>>(spart, Vbuf, out, p == 3);
  }
}